// Round 6
// baseline (226.156 us; speedup 1.0000x reference)
//
#include <hip/hip_runtime.h>
#include <stdint.h>

// Problem constants
#define Bdim 4
#define Nseq 2048
#define Dmod 1024
#define Hn   16
#define HD   64
#define SCALE 0.03125f   // D^-0.5 = 1/32
#define L2E   1.44269504089f

typedef __attribute__((ext_vector_type(8))) short short8;
typedef __attribute__((ext_vector_type(8))) unsigned short ushort8;
typedef __attribute__((ext_vector_type(4))) float f32x4;
typedef __attribute__((ext_vector_type(16))) float f32x16;

typedef __attribute__((address_space(3))) uint32_t lds_u32;
typedef __attribute__((address_space(1))) const uint32_t glob_u32;

static __device__ __forceinline__ void gload_lds16(const unsigned short* g, unsigned short* l) {
    __builtin_amdgcn_global_load_lds((glob_u32*)(const void*)g, (lds_u32*)(void*)l, 16, 0, 0);
}

static __device__ __forceinline__ unsigned short f2bf(float f) {
    union { float f; uint32_t u; } v; v.f = f;
    uint32_t r = (v.u + 0x7FFFu + ((v.u >> 16) & 1u)) >> 16;
    return (unsigned short)r;
}

// ---------------- cast x (fp32 -> bf16), vectorized ----------------
__global__ __launch_bounds__(256) void cast_x_kernel(const float* __restrict__ in,
                                                     unsigned short* __restrict__ out, int n4) {
    int i = blockIdx.x * blockDim.x + threadIdx.x;
    int stride = gridDim.x * blockDim.x;
    for (; i < n4; i += stride) {
        float4 v = reinterpret_cast<const float4*>(in)[i];
        ushort4 o;
        o.x = f2bf(v.x); o.y = f2bf(v.y); o.z = f2bf(v.z); o.w = f2bf(v.w);
        reinterpret_cast<ushort4*>(out)[i] = o;
    }
}

// ---------------- transpose + cast weights: out[c][r] = in[r][c] ----------------
__global__ void transpose_cast_kernel(const float* __restrict__ in,
                                      unsigned short* __restrict__ out, int R, int C) {
    __shared__ unsigned short t[32][33];
    int c0 = blockIdx.x * 32, r0 = blockIdx.y * 32;
    int tx = threadIdx.x, ty = threadIdx.y;
#pragma unroll
    for (int i = 0; i < 4; ++i)
        t[ty + i*8][tx] = f2bf(in[(size_t)(r0 + ty + i*8) * C + c0 + tx]);
    __syncthreads();
#pragma unroll
    for (int i = 0; i < 4; ++i)
        out[(size_t)(c0 + ty + i*8) * R + r0 + tx] = t[tx][ty + i*8];
}

// ---------------- bf16 GEMM (m97 structure + XCD-chunked remap) ----------------
// C[M,N] = A[M,K] * Bt[N,K]^T (+bias); 128x128 tile, BK=64, 4 waves.
template<bool OUT_BF16, bool BIAS>
__global__ __launch_bounds__(256) void gemm_bt_kernel(const unsigned short* __restrict__ A,
                                                      const unsigned short* __restrict__ Bt,
                                                      void* __restrict__ Cv,
                                                      const float* __restrict__ bias,
                                                      int M, int N, int K) {
    __shared__ unsigned short Al[128 * 64];   // linear: row stride 64 elem (128 B)
    __shared__ unsigned short Bl[128 * 64];
    int tid = threadIdx.x;
    int lane = tid & 63, wv = tid >> 6;
    int wr = (wv >> 1) * 64, wc = (wv & 1) * 64;
    int lr = lane & 15, lg = lane >> 4, lk = lg * 8;

    // XCD-chunked bijective remap (nwg % 8 == 0 for all our launches):
    // linear id % 8 selects the XCD; give each XCD a contiguous chunk of tiles.
    int gx = gridDim.x;
    int lin = blockIdx.y * gx + blockIdx.x;
    int cpx = (gx * gridDim.y) >> 3;
    int nl = (lin & 7) * cpx + (lin >> 3);
    int m0 = (nl / gx) * 128, n0 = (nl % gx) * 128;

    int srow = wv * 8 + (lane >> 3);
    int scol = (lane & 7) * 8;
    const unsigned short* ag = A  + (size_t)(m0 + srow) * K + scol;
    const unsigned short* bg = Bt + (size_t)(n0 + srow) * K + scol;
    unsigned short* la = Al + wv * 512;
    unsigned short* lb = Bl + wv * 512;

    f32x4 acc[4][4];
#pragma unroll
    for (int i = 0; i < 4; ++i)
#pragma unroll
        for (int j = 0; j < 4; ++j) acc[i][j] = (f32x4)0.f;

    for (int k0 = 0; k0 < K; k0 += 64) {
        __syncthreads();
#pragma unroll
        for (int i = 0; i < 4; ++i) {
            gload_lds16(ag + (size_t)i * 32 * K + k0, la + i * 2048);
            gload_lds16(bg + (size_t)i * 32 * K + k0, lb + i * 2048);
        }
        __syncthreads();
#pragma unroll
        for (int ks = 0; ks < 2; ++ks) {
            short8 a[4], b[4];
#pragma unroll
            for (int mi = 0; mi < 4; ++mi)
                a[mi] = *reinterpret_cast<const short8*>(Al + (wr + mi*16 + lr) * 64 + ks*32 + lk);
#pragma unroll
            for (int nj = 0; nj < 4; ++nj)
                b[nj] = *reinterpret_cast<const short8*>(Bl + (wc + nj*16 + lr) * 64 + ks*32 + lk);
#pragma unroll
            for (int mi = 0; mi < 4; ++mi)
#pragma unroll
                for (int nj = 0; nj < 4; ++nj)
                    acc[mi][nj] = __builtin_amdgcn_mfma_f32_16x16x32_bf16(a[mi], b[nj], acc[mi][nj], 0, 0, 0);
        }
    }
#pragma unroll
    for (int mi = 0; mi < 4; ++mi) {
#pragma unroll
        for (int nj = 0; nj < 4; ++nj) {
            int r = m0 + wr + mi*16 + lg*4;
            int c = n0 + wc + nj*16 + lr;
            float bv = BIAS ? bias[c] : 0.f;
#pragma unroll
            for (int i = 0; i < 4; ++i) {
                float v = acc[mi][nj][i] + bv;
                if (OUT_BF16)
                    reinterpret_cast<unsigned short*>(Cv)[(size_t)(r + i) * N + c] = f2bf(v);
                else
                    reinterpret_cast<float*>(Cv)[(size_t)(r + i) * N + c] = v;
            }
        }
    }
}

// ---------------- vT[bh][d][j] = qkv[b*N + j][2048 + h*64 + d] ----------------
__global__ __launch_bounds__(256) void transpose_v_kernel(const unsigned short* __restrict__ qkv,
                                                          unsigned short* __restrict__ vT) {
    __shared__ unsigned short t[64][68];
    int bh = blockIdx.y, b = bh >> 4, h = bh & 15;
    int j0 = blockIdx.x * 64;
    int tid = threadIdx.x;
#pragma unroll
    for (int p = 0; p < 4; ++p) {
        int e = p * 256 + tid;
        int jj = e >> 4;
        int d4 = (e & 15) * 4;
        const unsigned short* src = qkv + (size_t)(b*Nseq + j0 + jj) * 3072 + 2048 + h*64 + d4;
        ushort4 v = *reinterpret_cast<const ushort4*>(src);
        *reinterpret_cast<ushort4*>(&t[jj][d4]) = v;
    }
    __syncthreads();
#pragma unroll
    for (int p = 0; p < 4; ++p) {
        int e = p * 256 + tid;
        int d = e >> 4;
        int j4 = (e & 15) * 4;
        ushort4 v;
        v.x = t[j4 + 0][d]; v.y = t[j4 + 1][d]; v.z = t[j4 + 2][d]; v.w = t[j4 + 3][d];
        *reinterpret_cast<ushort4*>(vT + ((size_t)bh * 64 + d) * Nseq + j0 + j4) = v;
    }
}

// ---------------- flash attention: 64 q/wave, K/V double-buffered LDS (1 barrier/tile) ----------------
// S^T = mfma(K, Q): lane owns q = q0 + sub*32 + (lane&31); kv(reg) = (reg&3)+8*(reg>>2)+4*hi.
// P via per-wave LDS (k-map cancels); O^T = mfma(V^T, P). Defer-max (T13). setprio (T5).
__global__ __launch_bounds__(256, 2) void attn_kernel(const unsigned short* __restrict__ qkv,
                                                      const unsigned short* __restrict__ vT,
                                                      unsigned short* __restrict__ attn_o) {
    __shared__ unsigned short Kl[2 * 64 * 64];   // double-buffered (8192 B each)
    __shared__ unsigned short Vl[2 * 64 * 64];
    __shared__ unsigned short Pl[4 * 64 * 64];   // per-wave 64x64 P tile

    // bijective XCD-chunked swizzle: 512 blocks = 8 XCDs x 64
    int w = blockIdx.x;
    int lid = (w & 7) * 64 + (w >> 3);
    int bh = lid >> 3, qb = lid & 7;
    int b = bh >> 4, h = bh & 15;

    int tid = threadIdx.x, lane = tid & 63, wv = tid >> 6;
    int lr = lane & 31, hi = lane >> 5;
    int q0 = qb * 256 + wv * 64;

    // Q b-frags for both subtiles: qf[ks] = Q[q][d = ks*16 + hi*8 + j]
    short8 qfA[4], qfB[4];
    {
        const unsigned short* qrowA = qkv + (size_t)(b * Nseq + q0 + lr) * 3072 + h * 64 + hi * 8;
        const unsigned short* qrowB = qrowA + (size_t)32 * 3072;
#pragma unroll
        for (int ks = 0; ks < 4; ++ks) {
            qfA[ks] = *reinterpret_cast<const short8*>(qrowA + ks * 16);
            qfB[ks] = *reinterpret_cast<const short8*>(qrowB + ks * 16);
        }
    }

    float mrunA = -1e30f, lrunA = 0.f, mrunB = -1e30f, lrunB = 0.f;
    f32x16 oA0 = (f32x16)0.f, oA1 = (f32x16)0.f, oB0 = (f32x16)0.f, oB1 = (f32x16)0.f;

    // staging: thread t covers tile row sr, byte cols [sc, sc+32)
    int sr = tid >> 2;
    int sc = (tid & 3) * 32;
    const unsigned short* kg = qkv + (size_t)(b * Nseq + sr) * 3072 + 1024 + h * 64 + sc / 2;
    const unsigned short* vg = vT + ((size_t)(bh * 64 + sr)) * Nseq + sc / 2;
    int swz0 = sr * 128 + ((sc) ^ ((sr & 7) << 4));
    int swz1 = sr * 128 + ((sc + 16) ^ ((sr & 7) << 4));
    int rswz = (lr & 7) << 4;            // rows lr and lr+32 share lr&7
    char* PlW = (char*)Pl + wv * 8192 + lr * 128;

    // prologue: stage tile 0 into buffer 0
    {
        ushort8 a0 = *reinterpret_cast<const ushort8*>(kg);
        ushort8 a1 = *reinterpret_cast<const ushort8*>(kg + 8);
        ushort8 a2 = *reinterpret_cast<const ushort8*>(vg);
        ushort8 a3 = *reinterpret_cast<const ushort8*>(vg + 8);
        *reinterpret_cast<ushort8*>((char*)Kl + swz0) = a0;
        *reinterpret_cast<ushort8*>((char*)Kl + swz1) = a1;
        *reinterpret_cast<ushort8*>((char*)Vl + swz0) = a2;
        *reinterpret_cast<ushort8*>((char*)Vl + swz1) = a3;
    }
    // issue tile 1 loads (a full tile of latency cover)
    ushort8 k0r = *reinterpret_cast<const ushort8*>(kg + (size_t)64 * 3072);
    ushort8 k1r = *reinterpret_cast<const ushort8*>(kg + (size_t)64 * 3072 + 8);
    ushort8 v0r = *reinterpret_cast<const ushort8*>(vg + 64);
    ushort8 v1r = *reinterpret_cast<const ushort8*>(vg + 72);

    int cur = 0;
    for (int jt = 0; jt < Nseq; jt += 64, cur ^= 1) {
        __syncthreads();   // buf[cur] fully written by all waves
        int rb = cur * 8192, wb = rb ^ 8192;

        // ---- S^T = K · Q^T, K-frags read once, used by both subtiles ----
        f32x16 sA0 = (f32x16)0.f, sA1 = (f32x16)0.f, sB0 = (f32x16)0.f, sB1 = (f32x16)0.f;
        __builtin_amdgcn_s_setprio(1);
#pragma unroll
        for (int ks = 0; ks < 4; ++ks) {
            int cb = ks * 32 + hi * 16;
            short8 kf0 = *reinterpret_cast<const short8*>((char*)Kl + rb + lr * 128 + (cb ^ rswz));
            short8 kf1 = *reinterpret_cast<const short8*>((char*)Kl + rb + (lr + 32) * 128 + (cb ^ rswz));
            sA0 = __builtin_amdgcn_mfma_f32_32x32x16_bf16(kf0, qfA[ks], sA0, 0, 0, 0);
            sA1 = __builtin_amdgcn_mfma_f32_32x32x16_bf16(kf1, qfA[ks], sA1, 0, 0, 0);
            sB0 = __builtin_amdgcn_mfma_f32_32x32x16_bf16(kf0, qfB[ks], sB0, 0, 0, 0);
            sB1 = __builtin_amdgcn_mfma_f32_32x32x16_bf16(kf1, qfB[ks], sB1, 0, 0, 0);
        }
        __builtin_amdgcn_s_setprio(0);

        // ---- stage tile t+1 into buf[cur^1] (off critical path; barrier next iter publishes) ----
        if (jt + 64 < Nseq) {
            *reinterpret_cast<ushort8*>((char*)Kl + wb + swz0) = k0r;
            *reinterpret_cast<ushort8*>((char*)Kl + wb + swz1) = k1r;
            *reinterpret_cast<ushort8*>((char*)Vl + wb + swz0) = v0r;
            *reinterpret_cast<ushort8*>((char*)Vl + wb + swz1) = v1r;
            int jn = jt + 128;
            if (jn < Nseq) {   // issue tile t+2 loads
                k0r = *reinterpret_cast<const ushort8*>(kg + (size_t)jn * 3072);
                k1r = *reinterpret_cast<const ushort8*>(kg + (size_t)jn * 3072 + 8);
                v0r = *reinterpret_cast<const ushort8*>(vg + jn);
                v1r = *reinterpret_cast<const ushort8*>(vg + jn + 8);
            }
        }

        // ---- per-lane tile max for both subtiles ----
        float tA[16], tB[16];
#pragma unroll
        for (int i = 0; i < 16; ++i) { tA[i] = fmaxf(sA0[i], sA1[i]); tB[i] = fmaxf(sB0[i], sB1[i]); }
#pragma unroll
        for (int st = 8; st > 0; st >>= 1)
#pragma unroll
            for (int i = 0; i < st; ++i) { tA[i] = fmaxf(tA[i], tA[i + st]); tB[i] = fmaxf(tB[i], tB[i + st]); }
        float mlocA = fmaxf(tA[0], __shfl_xor(tA[0], 32)) * SCALE;
        float mlocB = fmaxf(tB[0], __shfl_xor(tB[0], 32)) * SCALE;

        // ---- defer-max (T13): rescale only when max grew > 8 ----
        if (!__all((mlocA <= mrunA + 8.f) && (mlocB <= mrunB + 8.f))) {
            float mnA = fmaxf(mrunA, mlocA);
            float fA = __builtin_amdgcn_exp2f((mrunA - mnA) * L2E);
            float mnB = fmaxf(mrunB, mlocB);
            float fB = __builtin_amdgcn_exp2f((mrunB - mnB) * L2E);
            lrunA *= fA; lrunB *= fB; mrunA = mnA; mrunB = mnB;
#pragma unroll
            for (int i = 0; i < 16; ++i) {
                oA0[i] *= fA; oA1[i] *= fA; oB0[i] *= fB; oB1[i] *= fB;
            }
        }

        // ---- P = exp2(s*c1 + c0) ----
        const float c1 = SCALE * L2E;
        float c0A = -mrunA * L2E, c0B = -mrunB * L2E;
        float pA0[16], pA1[16], pB0[16], pB1[16];
#pragma unroll
        for (int i = 0; i < 16; ++i) {
            pA0[i] = __builtin_amdgcn_exp2f(fmaf(sA0[i], c1, c0A));
            pA1[i] = __builtin_amdgcn_exp2f(fmaf(sA1[i], c1, c0A));
            pB0[i] = __builtin_amdgcn_exp2f(fmaf(sB0[i], c1, c0B));
            pB1[i] = __builtin_amdgcn_exp2f(fmaf(sB1[i], c1, c0B));
        }

        // ---- pack + write P (both subtiles), swizzled b64; sum trees fill LDS latency ----
        uint32_t WA[16], WB[16];
#pragma unroll
        for (int m = 0; m < 8; ++m) {
            asm("v_cvt_pk_bf16_f32 %0, %1, %2" : "=v"(WA[m])   : "v"(pA0[2*m]), "v"(pA0[2*m+1]));
            asm("v_cvt_pk_bf16_f32 %0, %1, %2" : "=v"(WA[8+m]) : "v"(pA1[2*m]), "v"(pA1[2*m+1]));
            asm("v_cvt_pk_bf16_f32 %0, %1, %2" : "=v"(WB[m])   : "v"(pB0[2*m]), "v"(pB0[2*m+1]));
            asm("v_cvt_pk_bf16_f32 %0, %1, %2" : "=v"(WB[8+m]) : "v"(pB1[2*m]), "v"(pB1[2*m+1]));
        }
#pragma unroll
        for (int tt = 0; tt < 8; ++tt) {
            uint64_t valA = (uint64_t)WA[2*tt] | ((uint64_t)WA[2*tt+1] << 32);
            uint64_t valB = (uint64_t)WB[2*tt] | ((uint64_t)WB[2*tt+1] << 32);
            int off = (16*tt + 8*hi) ^ rswz;
            *reinterpret_cast<uint64_t*>(PlW + off) = valA;
            *reinterpret_cast<uint64_t*>(PlW + 4096 + off) = valB;
        }

        float aA[16], aB[16];
#pragma unroll
        for (int i = 0; i < 16; ++i) { aA[i] = pA0[i] + pA1[i]; aB[i] = pB0[i] + pB1[i]; }
#pragma unroll
        for (int st = 8; st > 0; st >>= 1)
#pragma unroll
            for (int i = 0; i < st; ++i) { aA[i] += aA[i + st]; aB[i] += aB[i + st]; }
        lrunA += aA[0] + __shfl_xor(aA[0], 32);
        lrunB += aB[0] + __shfl_xor(aB[0], 32);

        // ---- O^T += V^T · P : V-frags read once, used by both subtiles ----
        __builtin_amdgcn_s_setprio(1);
#pragma unroll
        for (int ks4 = 0; ks4 < 4; ++ks4) {
            int cb = ks4 * 32 + hi * 16;
            short8 vf0 = *reinterpret_cast<const short8*>((char*)Vl + rb + lr * 128 + (cb ^ rswz));
            short8 vf1 = *reinterpret_cast<const short8*>((char*)Vl + rb + (lr + 32) * 128 + (cb ^ rswz));
            short8 pfA = *reinterpret_cast<const short8*>(PlW + (cb ^ rswz));
            short8 pfB = *reinterpret_cast<const short8*>(PlW + 4096 + (cb ^ rswz));
            oA0 = __builtin_amdgcn_mfma_f32_32x32x16_bf16(vf0, pfA, oA0, 0, 0, 0);
            oA1 = __builtin_amdgcn_mfma_f32_32x32x16_bf16(vf1, pfA, oA1, 0, 0, 0);
            oB0 = __builtin_amdgcn_mfma_f32_32x32x16_bf16(vf0, pfB, oB0, 0, 0, 0);
            oB1 = __builtin_amdgcn_mfma_f32_32x32x16_bf16(vf1, pfB, oB1, 0, 0, 0);
        }
        __builtin_amdgcn_s_setprio(0);
    }

    // ---- epilogue: O^T[d][q] -> attn_o[b*N + q][h*64 + d] ----
    float invA = 1.f / lrunA, invB = 1.f / lrunB;
    unsigned short* orowA = attn_o + (size_t)(b * Nseq + q0 + lr) * Dmod + h * 64;
    unsigned short* orowB = attn_o + (size_t)(b * Nseq + q0 + 32 + lr) * Dmod + h * 64;
#pragma unroll
    for (int db = 0; db < 2; ++db)
#pragma unroll
        for (int g = 0; g < 4; ++g) {
            int d = db * 32 + 8 * g + 4 * hi;
            ushort4 o4;
            o4.x = f2bf((db ? oA1[4*g+0] : oA0[4*g+0]) * invA);
            o4.y = f2bf((db ? oA1[4*g+1] : oA0[4*g+1]) * invA);
            o4.z = f2bf((db ? oA1[4*g+2] : oA0[4*g+2]) * invA);
            o4.w = f2bf((db ? oA1[4*g+3] : oA0[4*g+3]) * invA);
            *reinterpret_cast<ushort4*>(orowA + d) = o4;
            o4.x = f2bf((db ? oB1[4*g+0] : oB0[4*g+0]) * invB);
            o4.y = f2bf((db ? oB1[4*g+1] : oB0[4*g+1]) * invB);
            o4.z = f2bf((db ? oB1[4*g+2] : oB0[4*g+2]) * invB);
            o4.w = f2bf((db ? oB1[4*g+3] : oB0[4*g+3]) * invB);
            *reinterpret_cast<ushort4*>(orowB + d) = o4;
        }
}

// ---------------- launch ----------------
extern "C" void kernel_launch(void* const* d_in, const int* in_sizes, int n_in,
                              void* d_out, int out_size, void* d_ws, size_t ws_size,
                              hipStream_t stream) {
    const float* x      = (const float*)d_in[0];
    const float* w_qkv  = (const float*)d_in[1];
    const float* w_proj = (const float*)d_in[2];
    const float* b_proj = (const float*)d_in[3];
    float* out = (float*)d_out;
    char* ws = (char*)d_ws;

    unsigned short* qkv    = (unsigned short*)(ws);               // 50331648 B
    unsigned short* vT     = (unsigned short*)(ws + 50331648);    // 16777216 B
    unsigned short* xb     = (unsigned short*)(ws + 67108864);    // 16777216 B (reused as attn_o)
    unsigned short* attn_o = xb;
    unsigned short* wqkvT  = (unsigned short*)(ws + 83886080);    // 6291456 B
    unsigned short* wprojT = (unsigned short*)(ws + 90177536);    // 2097152 B

    cast_x_kernel<<<2048, 256, 0, stream>>>(x, xb, (Bdim*Nseq*Dmod)/4);
    transpose_cast_kernel<<<dim3(3072/32, 1024/32), dim3(32, 8), 0, stream>>>(w_qkv, wqkvT, 1024, 3072);
    transpose_cast_kernel<<<dim3(1024/32, 1024/32), dim3(32, 8), 0, stream>>>(w_proj, wprojT, 1024, 1024);
    gemm_bt_kernel<true, false><<<dim3(3072/128, 8192/128), 256, 0, stream>>>(
        xb, wqkvT, qkv, nullptr, Bdim*Nseq, 3*Dmod, Dmod);
    transpose_v_kernel<<<dim3(Nseq/64, Bdim*Hn), 256, 0, stream>>>(qkv, vT);
    attn_kernel<<<512, 256, 0, stream>>>(qkv, vT, attn_o);
    gemm_bt_kernel<false, true><<<dim3(1024/128, 8192/128), 256, 0, stream>>>(
        attn_o, wprojT, out, b_proj, Bdim*Nseq, Dmod, Dmod);
}

// Round 7
// 223.922 us; speedup vs baseline: 1.0100x; 1.0100x over previous
//
#include <hip/hip_runtime.h>
#include <stdint.h>

// Problem constants
#define Bdim 4
#define Nseq 2048
#define Dmod 1024
#define Hn   16
#define HD   64
#define SCALE 0.03125f   // D^-0.5 = 1/32
#define L2E   1.44269504089f

typedef __attribute__((ext_vector_type(8))) short short8;
typedef __attribute__((ext_vector_type(8))) unsigned short ushort8;
typedef __attribute__((ext_vector_type(4))) float f32x4;
typedef __attribute__((ext_vector_type(16))) float f32x16;

typedef __attribute__((address_space(3))) uint32_t lds_u32;
typedef __attribute__((address_space(1))) const uint32_t glob_u32;

static __device__ __forceinline__ void gload_lds16(const unsigned short* g, unsigned short* l) {
    __builtin_amdgcn_global_load_lds((glob_u32*)(const void*)g, (lds_u32*)(void*)l, 16, 0, 0);
}

static __device__ __forceinline__ unsigned short f2bf(float f) {
    union { float f; uint32_t u; } v; v.f = f;
    uint32_t r = (v.u + 0x7FFFu + ((v.u >> 16) & 1u)) >> 16;
    return (unsigned short)r;
}

// ---------------- cast x (fp32 -> bf16), vectorized ----------------
__global__ __launch_bounds__(256) void cast_x_kernel(const float* __restrict__ in,
                                                     unsigned short* __restrict__ out, int n4) {
    int i = blockIdx.x * blockDim.x + threadIdx.x;
    int stride = gridDim.x * blockDim.x;
    for (; i < n4; i += stride) {
        float4 v = reinterpret_cast<const float4*>(in)[i];
        ushort4 o;
        o.x = f2bf(v.x); o.y = f2bf(v.y); o.z = f2bf(v.z); o.w = f2bf(v.w);
        reinterpret_cast<ushort4*>(out)[i] = o;
    }
}

// ---------------- transpose + cast weights: out[c][r] = in[r][c] ----------------
__global__ void transpose_cast_kernel(const float* __restrict__ in,
                                      unsigned short* __restrict__ out, int R, int C) {
    __shared__ unsigned short t[32][33];
    int c0 = blockIdx.x * 32, r0 = blockIdx.y * 32;
    int tx = threadIdx.x, ty = threadIdx.y;
#pragma unroll
    for (int i = 0; i < 4; ++i)
        t[ty + i*8][tx] = f2bf(in[(size_t)(r0 + ty + i*8) * C + c0 + tx]);
    __syncthreads();
#pragma unroll
    for (int i = 0; i < 4; ++i)
        out[(size_t)(c0 + ty + i*8) * R + r0 + tx] = t[tx][ty + i*8];
}

// ---------------- bf16 GEMM (m97 structure + XCD remap + optional V->vT redirect) ----------------
// C[M,N] = A[M,K] * Bt[N,K]^T (+bias); 128x128 tile, BK=64, 4 waves.
// VSPLIT: columns c>=2048 (the V third of qkv) are written transposed into vTp
//         as vT[bh][d][j] instead of into C — fuses the old transpose_v kernel.
template<bool OUT_BF16, bool BIAS, bool VSPLIT>
__global__ __launch_bounds__(256) void gemm_bt_kernel(const unsigned short* __restrict__ A,
                                                      const unsigned short* __restrict__ Bt,
                                                      void* __restrict__ Cv,
                                                      const float* __restrict__ bias,
                                                      unsigned short* __restrict__ vTp,
                                                      int M, int N, int K) {
    __shared__ unsigned short Al[128 * 64];   // linear: row stride 64 elem (128 B)
    __shared__ unsigned short Bl[128 * 64];
    int tid = threadIdx.x;
    int lane = tid & 63, wv = tid >> 6;
    int wr = (wv >> 1) * 64, wc = (wv & 1) * 64;
    int lr = lane & 15, lg = lane >> 4, lk = lg * 8;

    // XCD-chunked bijective remap (nwg % 8 == 0 for all our launches)
    int gx = gridDim.x;
    int lin = blockIdx.y * gx + blockIdx.x;
    int cpx = (gx * gridDim.y) >> 3;
    int nl = (lin & 7) * cpx + (lin >> 3);
    int m0 = (nl / gx) * 128, n0 = (nl % gx) * 128;

    int srow = wv * 8 + (lane >> 3);
    int scol = (lane & 7) * 8;
    const unsigned short* ag = A  + (size_t)(m0 + srow) * K + scol;
    const unsigned short* bg = Bt + (size_t)(n0 + srow) * K + scol;
    unsigned short* la = Al + wv * 512;
    unsigned short* lb = Bl + wv * 512;

    f32x4 acc[4][4];
#pragma unroll
    for (int i = 0; i < 4; ++i)
#pragma unroll
        for (int j = 0; j < 4; ++j) acc[i][j] = (f32x4)0.f;

    for (int k0 = 0; k0 < K; k0 += 64) {
        __syncthreads();
#pragma unroll
        for (int i = 0; i < 4; ++i) {
            gload_lds16(ag + (size_t)i * 32 * K + k0, la + i * 2048);
            gload_lds16(bg + (size_t)i * 32 * K + k0, lb + i * 2048);
        }
        __syncthreads();
#pragma unroll
        for (int ks = 0; ks < 2; ++ks) {
            short8 a[4], b[4];
#pragma unroll
            for (int mi = 0; mi < 4; ++mi)
                a[mi] = *reinterpret_cast<const short8*>(Al + (wr + mi*16 + lr) * 64 + ks*32 + lk);
#pragma unroll
            for (int nj = 0; nj < 4; ++nj)
                b[nj] = *reinterpret_cast<const short8*>(Bl + (wc + nj*16 + lr) * 64 + ks*32 + lk);
#pragma unroll
            for (int mi = 0; mi < 4; ++mi)
#pragma unroll
                for (int nj = 0; nj < 4; ++nj)
                    acc[mi][nj] = __builtin_amdgcn_mfma_f32_16x16x32_bf16(a[mi], b[nj], acc[mi][nj], 0, 0, 0);
        }
    }
#pragma unroll
    for (int mi = 0; mi < 4; ++mi) {
#pragma unroll
        for (int nj = 0; nj < 4; ++nj) {
            int r = m0 + wr + mi*16 + lg*4;
            int c = n0 + wc + nj*16 + lr;
            if (VSPLIT && c >= 2048) {
                // vT[bh][d][j]: bh = b*16 + h, d = c&63, j = r&2047 (+i contiguous)
                int cc = c - 2048;
                int bh = ((r >> 11) << 4) + (cc >> 6);
                int d = cc & 63;
                ushort4 o4;
                o4.x = f2bf(acc[mi][nj][0]);
                o4.y = f2bf(acc[mi][nj][1]);
                o4.z = f2bf(acc[mi][nj][2]);
                o4.w = f2bf(acc[mi][nj][3]);
                *reinterpret_cast<ushort4*>(vTp + ((size_t)(bh * 64 + d) * 2048) + (r & 2047)) = o4;
            } else {
                float bv = BIAS ? bias[c] : 0.f;
#pragma unroll
                for (int i = 0; i < 4; ++i) {
                    float v = acc[mi][nj][i] + bv;
                    if (OUT_BF16)
                        reinterpret_cast<unsigned short*>(Cv)[(size_t)(r + i) * N + c] = f2bf(v);
                    else
                        reinterpret_cast<float*>(Cv)[(size_t)(r + i) * N + c] = v;
                }
            }
        }
    }
}

// ---------------- flash attention: 64 q/wave, dbuf K/V, FRAGMENT-LINEAR LDS (conflict-free) ----------------
// Fragment-linear: each 32x32x16 operand fragment lives in a contiguous 1KB block;
// reader lane l reads bytes [l*16, l*16+16). All ds_read_b128 are bank-sequential.
// K tile: elem (kv,d) -> (kv>>5)*4096 + (d>>4)*1024 + ((kv&31) + 32*((d>>3)&1))*16 + (d&7)*2
// V tile: elem (d,kv) -> (d>>5)*4096 + (kv>>4)*1024 + ((d&31) + 32*((kv>>3)&1))*16 + (kv&7)*2
// P tile (per wave, per subtile): elem (q,kv) -> (kv>>4)*1024 + ((q&31) + 32*((kv>>3)&1))*16 + (kv&7)*2
// Both MFMA operands always placed with the same assumed lane->k map -> map errors cancel.
__global__ __launch_bounds__(256, 2) void attn_kernel(const unsigned short* __restrict__ qkv,
                                                      const unsigned short* __restrict__ vT,
                                                      unsigned short* __restrict__ attn_o) {
    __shared__ unsigned short Kl[2 * 64 * 64];   // double-buffered, 8192 B each
    __shared__ unsigned short Vl[2 * 64 * 64];
    __shared__ unsigned short Pl[4 * 64 * 64];   // per-wave 8192 B (subtile A, then B)

    // bijective XCD-chunked swizzle: 512 blocks = 8 XCDs x 64
    int w = blockIdx.x;
    int lid = (w & 7) * 64 + (w >> 3);
    int bh = lid >> 3, qb = lid & 7;
    int b = bh >> 4, h = bh & 15;

    int tid = threadIdx.x, lane = tid & 63, wv = tid >> 6;
    int lr = lane & 31, hi = lane >> 5;
    int q0 = qb * 256 + wv * 64;

    // Q b-frags for both subtiles: qf[ks] elem j = Q[q][ks*16 + hi*8 + j]  (assumed map)
    short8 qfA[4], qfB[4];
    {
        const unsigned short* qrowA = qkv + (size_t)(b * Nseq + q0 + lr) * 3072 + h * 64 + hi * 8;
        const unsigned short* qrowB = qrowA + (size_t)32 * 3072;
#pragma unroll
        for (int ks = 0; ks < 4; ++ks) {
            qfA[ks] = *reinterpret_cast<const short8*>(qrowA + ks * 16);
            qfB[ks] = *reinterpret_cast<const short8*>(qrowB + ks * 16);
        }
    }

    float mrunA = -1e30f, lrunA = 0.f, mrunB = -1e30f, lrunB = 0.f;
    f32x16 oA0 = (f32x16)0.f, oA1 = (f32x16)0.f, oB0 = (f32x16)0.f, oB1 = (f32x16)0.f;

    // staging: thread t covers K row sr (kv), d block (tid&3)*16  /  V row sr (d), kv block (tid&3)*16
    int sr = tid >> 2;
    const unsigned short* kg = qkv + (size_t)(b * Nseq + sr) * 3072 + 1024 + h * 64 + (tid & 3) * 16;
    const unsigned short* vg = vT + ((size_t)(bh * 64 + sr)) * Nseq + (tid & 3) * 16;
    // fragment-linear staging offset (chunk0; chunk1 = +512): same formula for K and V tiles
    int sb = (sr >> 5) * 4096 + (tid & 3) * 1024 + (sr & 31) * 16;
    char* Pw = (char*)Pl + wv * 8192 + lr * 16 + 8 * hi;   // + (t>>1)*1024 + (t&1)*512 per b64
    char* Pr = (char*)Pl + wv * 8192 + lane * 16;          // + ks4*1024 (subtile A), +4096 (B)

    // prologue: stage tile 0 into buffer 0
    {
        ushort8 a0 = *reinterpret_cast<const ushort8*>(kg);
        ushort8 a1 = *reinterpret_cast<const ushort8*>(kg + 8);
        ushort8 a2 = *reinterpret_cast<const ushort8*>(vg);
        ushort8 a3 = *reinterpret_cast<const ushort8*>(vg + 8);
        *reinterpret_cast<ushort8*>((char*)Kl + sb) = a0;
        *reinterpret_cast<ushort8*>((char*)Kl + sb + 512) = a1;
        *reinterpret_cast<ushort8*>((char*)Vl + sb) = a2;
        *reinterpret_cast<ushort8*>((char*)Vl + sb + 512) = a3;
    }
    // issue tile 1 loads
    ushort8 k0r = *reinterpret_cast<const ushort8*>(kg + (size_t)64 * 3072);
    ushort8 k1r = *reinterpret_cast<const ushort8*>(kg + (size_t)64 * 3072 + 8);
    ushort8 v0r = *reinterpret_cast<const ushort8*>(vg + 64);
    ushort8 v1r = *reinterpret_cast<const ushort8*>(vg + 72);

    int cur = 0;
    for (int jt = 0; jt < Nseq; jt += 64, cur ^= 1) {
        __syncthreads();   // buf[cur] fully written by all waves
        int rb = cur * 8192, wb = rb ^ 8192;

        // ---- S^T = K · Q^T : kf reads are contiguous 1KB blocks, conflict-free ----
        f32x16 sA0 = (f32x16)0.f, sA1 = (f32x16)0.f, sB0 = (f32x16)0.f, sB1 = (f32x16)0.f;
        __builtin_amdgcn_s_setprio(1);
#pragma unroll
        for (int ks = 0; ks < 4; ++ks) {
            short8 kf0 = *reinterpret_cast<const short8*>((char*)Kl + rb + ks*1024 + lane*16);
            short8 kf1 = *reinterpret_cast<const short8*>((char*)Kl + rb + 4096 + ks*1024 + lane*16);
            sA0 = __builtin_amdgcn_mfma_f32_32x32x16_bf16(kf0, qfA[ks], sA0, 0, 0, 0);
            sA1 = __builtin_amdgcn_mfma_f32_32x32x16_bf16(kf1, qfA[ks], sA1, 0, 0, 0);
            sB0 = __builtin_amdgcn_mfma_f32_32x32x16_bf16(kf0, qfB[ks], sB0, 0, 0, 0);
            sB1 = __builtin_amdgcn_mfma_f32_32x32x16_bf16(kf1, qfB[ks], sB1, 0, 0, 0);
        }
        __builtin_amdgcn_s_setprio(0);

        // ---- stage tile t+1 into buf[cur^1] (off critical path) ----
        if (jt + 64 < Nseq) {
            *reinterpret_cast<ushort8*>((char*)Kl + wb + sb) = k0r;
            *reinterpret_cast<ushort8*>((char*)Kl + wb + sb + 512) = k1r;
            *reinterpret_cast<ushort8*>((char*)Vl + wb + sb) = v0r;
            *reinterpret_cast<ushort8*>((char*)Vl + wb + sb + 512) = v1r;
            int jn = jt + 128;
            if (jn < Nseq) {
                k0r = *reinterpret_cast<const ushort8*>(kg + (size_t)jn * 3072);
                k1r = *reinterpret_cast<const ushort8*>(kg + (size_t)jn * 3072 + 8);
                v0r = *reinterpret_cast<const ushort8*>(vg + jn);
                v1r = *reinterpret_cast<const ushort8*>(vg + jn + 8);
            }
        }

        // ---- per-lane tile max for both subtiles ----
        float tA[16], tB[16];
#pragma unroll
        for (int i = 0; i < 16; ++i) { tA[i] = fmaxf(sA0[i], sA1[i]); tB[i] = fmaxf(sB0[i], sB1[i]); }
#pragma unroll
        for (int st = 8; st > 0; st >>= 1)
#pragma unroll
            for (int i = 0; i < st; ++i) { tA[i] = fmaxf(tA[i], tA[i + st]); tB[i] = fmaxf(tB[i], tB[i + st]); }
        float mlocA = fmaxf(tA[0], __shfl_xor(tA[0], 32)) * SCALE;
        float mlocB = fmaxf(tB[0], __shfl_xor(tB[0], 32)) * SCALE;

        // ---- defer-max (T13): rescale only when max grew > 8 ----
        if (!__all((mlocA <= mrunA + 8.f) && (mlocB <= mrunB + 8.f))) {
            float mnA = fmaxf(mrunA, mlocA);
            float fA = __builtin_amdgcn_exp2f((mrunA - mnA) * L2E);
            float mnB = fmaxf(mrunB, mlocB);
            float fB = __builtin_amdgcn_exp2f((mrunB - mnB) * L2E);
            lrunA *= fA; lrunB *= fB; mrunA = mnA; mrunB = mnB;
#pragma unroll
            for (int i = 0; i < 16; ++i) {
                oA0[i] *= fA; oA1[i] *= fA; oB0[i] *= fB; oB1[i] *= fB;
            }
        }

        // ---- P = exp2(s*c1 + c0) ----
        const float c1 = SCALE * L2E;
        float c0A = -mrunA * L2E, c0B = -mrunB * L2E;
        float pA0[16], pA1[16], pB0[16], pB1[16];
#pragma unroll
        for (int i = 0; i < 16; ++i) {
            pA0[i] = __builtin_amdgcn_exp2f(fmaf(sA0[i], c1, c0A));
            pA1[i] = __builtin_amdgcn_exp2f(fmaf(sA1[i], c1, c0A));
            pB0[i] = __builtin_amdgcn_exp2f(fmaf(sB0[i], c1, c0B));
            pB1[i] = __builtin_amdgcn_exp2f(fmaf(sB1[i], c1, c0B));
        }

        // ---- pack + write P, fragment-linear b64 stores (conflict-free) ----
        uint32_t WA[16], WB[16];
#pragma unroll
        for (int m = 0; m < 8; ++m) {
            asm("v_cvt_pk_bf16_f32 %0, %1, %2" : "=v"(WA[m])   : "v"(pA0[2*m]), "v"(pA0[2*m+1]));
            asm("v_cvt_pk_bf16_f32 %0, %1, %2" : "=v"(WA[8+m]) : "v"(pA1[2*m]), "v"(pA1[2*m+1]));
            asm("v_cvt_pk_bf16_f32 %0, %1, %2" : "=v"(WB[m])   : "v"(pB0[2*m]), "v"(pB0[2*m+1]));
            asm("v_cvt_pk_bf16_f32 %0, %1, %2" : "=v"(WB[8+m]) : "v"(pB1[2*m]), "v"(pB1[2*m+1]));
        }
#pragma unroll
        for (int tt = 0; tt < 8; ++tt) {
            uint64_t valA = (uint64_t)WA[2*tt] | ((uint64_t)WA[2*tt+1] << 32);
            uint64_t valB = (uint64_t)WB[2*tt] | ((uint64_t)WB[2*tt+1] << 32);
            char* pa = Pw + (tt >> 1) * 1024 + (tt & 1) * 512;
            *reinterpret_cast<uint64_t*>(pa) = valA;
            *reinterpret_cast<uint64_t*>(pa + 4096) = valB;
        }

        float aA[16], aB[16];
#pragma unroll
        for (int i = 0; i < 16; ++i) { aA[i] = pA0[i] + pA1[i]; aB[i] = pB0[i] + pB1[i]; }
#pragma unroll
        for (int st = 8; st > 0; st >>= 1)
#pragma unroll
            for (int i = 0; i < st; ++i) { aA[i] += aA[i + st]; aB[i] += aB[i + st]; }
        lrunA += aA[0] + __shfl_xor(aA[0], 32);
        lrunB += aB[0] + __shfl_xor(aB[0], 32);

        // ---- O^T += V^T · P : all reads contiguous 1KB fragment blocks ----
        __builtin_amdgcn_s_setprio(1);
#pragma unroll
        for (int ks4 = 0; ks4 < 4; ++ks4) {
            short8 vf0 = *reinterpret_cast<const short8*>((char*)Vl + rb + ks4*1024 + lane*16);
            short8 vf1 = *reinterpret_cast<const short8*>((char*)Vl + rb + 4096 + ks4*1024 + lane*16);
            short8 pfA = *reinterpret_cast<const short8*>(Pr + ks4*1024);
            short8 pfB = *reinterpret_cast<const short8*>(Pr + 4096 + ks4*1024);
            oA0 = __builtin_amdgcn_mfma_f32_32x32x16_bf16(vf0, pfA, oA0, 0, 0, 0);
            oA1 = __builtin_amdgcn_mfma_f32_32x32x16_bf16(vf1, pfA, oA1, 0, 0, 0);
            oB0 = __builtin_amdgcn_mfma_f32_32x32x16_bf16(vf0, pfB, oB0, 0, 0, 0);
            oB1 = __builtin_amdgcn_mfma_f32_32x32x16_bf16(vf1, pfB, oB1, 0, 0, 0);
        }
        __builtin_amdgcn_s_setprio(0);
    }

    // ---- epilogue: O^T[d][q] -> attn_o[b*N + q][h*64 + d] ----
    float invA = 1.f / lrunA, invB = 1.f / lrunB;
    unsigned short* orowA = attn_o + (size_t)(b * Nseq + q0 + lr) * Dmod + h * 64;
    unsigned short* orowB = attn_o + (size_t)(b * Nseq + q0 + 32 + lr) * Dmod + h * 64;
#pragma unroll
    for (int db = 0; db < 2; ++db)
#pragma unroll
        for (int g = 0; g < 4; ++g) {
            int d = db * 32 + 8 * g + 4 * hi;
            ushort4 o4;
            o4.x = f2bf((db ? oA1[4*g+0] : oA0[4*g+0]) * invA);
            o4.y = f2bf((db ? oA1[4*g+1] : oA0[4*g+1]) * invA);
            o4.z = f2bf((db ? oA1[4*g+2] : oA0[4*g+2]) * invA);
            o4.w = f2bf((db ? oA1[4*g+3] : oA0[4*g+3]) * invA);
            *reinterpret_cast<ushort4*>(orowA + d) = o4;
            o4.x = f2bf((db ? oB1[4*g+0] : oB0[4*g+0]) * invB);
            o4.y = f2bf((db ? oB1[4*g+1] : oB0[4*g+1]) * invB);
            o4.z = f2bf((db ? oB1[4*g+2] : oB0[4*g+2]) * invB);
            o4.w = f2bf((db ? oB1[4*g+3] : oB0[4*g+3]) * invB);
            *reinterpret_cast<ushort4*>(orowB + d) = o4;
        }
}

// ---------------- launch ----------------
extern "C" void kernel_launch(void* const* d_in, const int* in_sizes, int n_in,
                              void* d_out, int out_size, void* d_ws, size_t ws_size,
                              hipStream_t stream) {
    const float* x      = (const float*)d_in[0];
    const float* w_qkv  = (const float*)d_in[1];
    const float* w_proj = (const float*)d_in[2];
    const float* b_proj = (const float*)d_in[3];
    float* out = (float*)d_out;
    char* ws = (char*)d_ws;

    unsigned short* qkv    = (unsigned short*)(ws);               // 50331648 B (V third unused)
    unsigned short* vT     = (unsigned short*)(ws + 50331648);    // 16777216 B
    unsigned short* xb     = (unsigned short*)(ws + 67108864);    // 16777216 B (reused as attn_o)
    unsigned short* attn_o = xb;
    unsigned short* wqkvT  = (unsigned short*)(ws + 83886080);    // 6291456 B
    unsigned short* wprojT = (unsigned short*)(ws + 90177536);    // 2097152 B

    cast_x_kernel<<<2048, 256, 0, stream>>>(x, xb, (Bdim*Nseq*Dmod)/4);
    transpose_cast_kernel<<<dim3(3072/32, 1024/32), dim3(32, 8), 0, stream>>>(w_qkv, wqkvT, 1024, 3072);
    transpose_cast_kernel<<<dim3(1024/32, 1024/32), dim3(32, 8), 0, stream>>>(w_proj, wprojT, 1024, 1024);
    // qkv = x @ w_qkv; V columns redirected (transposed) into vT
    gemm_bt_kernel<true, false, true><<<dim3(3072/128, 8192/128), 256, 0, stream>>>(
        xb, wqkvT, qkv, nullptr, vT, Bdim*Nseq, 3*Dmod, Dmod);
    attn_kernel<<<512, 256, 0, stream>>>(qkv, vT, attn_o);
    gemm_bt_kernel<false, true, false><<<dim3(1024/128, 8192/128), 256, 0, stream>>>(
        attn_o, wprojT, out, b_proj, nullptr, Bdim*Nseq, Dmod, Dmod);
}